// Round 1
// baseline (310.660 us; speedup 1.0000x reference)
//
#include <hip/hip_runtime.h>
#include <math.h>

// KWinners2d: x (128,256,32,32) f32, dutyCycle (1,256,1,1) f32
// k = round(0.1 * 256*32*32) = 26214 per batch row.
// Radix-select (11+11+10 bits) on order-preserving uint key, then mask pass.

#define NB 128
#define NC 256
#define HW_SZ 1024
#define ROW_N (NC * HW_SZ)      // 262144
#define K_SEL 26214u
#define BINS1 2048
#define BINS3 1024
#define BPR 16                  // blocks per row for streaming kernels
#define SLICE (ROW_N / BPR)     // 16384 elements per block
#define NTHREADS 256

__device__ __forceinline__ unsigned int f2key(float f) {
    unsigned int u = __float_as_uint(f);
    return (u & 0x80000000u) ? ~u : (u | 0x80000000u);
}
__device__ __forceinline__ float key2f(unsigned int k) {
    unsigned int u = (k & 0x80000000u) ? (k ^ 0x80000000u) : ~k;
    return __uint_as_float(u);
}

// boost[c] = exp(target_density - duty[c]); fp32 subtract (exact match to JAX),
// exp in double -> correctly-rounded fp32.
__global__ void boost_kernel(const float* __restrict__ duty, float* __restrict__ boost) {
    const int c = threadIdx.x;
    const float td = 26214.0f / 262144.0f;   // exact in fp32
    float diff = td - duty[c];
    boost[c] = (float)exp((double)diff);
}

// Pass 1: per-row histogram of top 11 bits of key.
__global__ void __launch_bounds__(NTHREADS) hist1_kernel(const float* __restrict__ x,
        const float* __restrict__ boost, unsigned int* __restrict__ hist) {
    __shared__ unsigned int h[BINS1];
    __shared__ float bl[16];
    const int blk = blockIdx.x;
    const int row = blk >> 4;
    const int j = blk & 15;
    for (int i = threadIdx.x; i < BINS1; i += NTHREADS) h[i] = 0u;
    if (threadIdx.x < 16) bl[threadIdx.x] = boost[j * 16 + threadIdx.x];
    __syncthreads();
    const float4* __restrict__ xp =
        (const float4*)(x + (size_t)row * ROW_N + (size_t)j * SLICE);
    const int t = threadIdx.x;
#pragma unroll
    for (int i = 0; i < SLICE / (4 * NTHREADS); ++i) {
        const int idx4 = t + i * NTHREADS;
        float4 v = xp[idx4];
        const float b = bl[(idx4 * 4) >> 10];   // 4 consecutive elems share channel
        atomicAdd(&h[f2key(v.x * b) >> 21], 1u);
        atomicAdd(&h[f2key(v.y * b) >> 21], 1u);
        atomicAdd(&h[f2key(v.z * b) >> 21], 1u);
        atomicAdd(&h[f2key(v.w * b) >> 21], 1u);
    }
    __syncthreads();
    unsigned int* __restrict__ gh = hist + (size_t)row * BINS1;
    for (int i = threadIdx.x; i < BINS1; i += NTHREADS)
        if (h[i]) atomicAdd(&gh[i], h[i]);
}

// Pass 2: histogram of bits [20:10] for elements whose top-11 == bin1[row].
__global__ void __launch_bounds__(NTHREADS) hist2_kernel(const float* __restrict__ x,
        const float* __restrict__ boost, const unsigned int* __restrict__ bin1,
        unsigned int* __restrict__ hist) {
    __shared__ unsigned int h[BINS1];
    __shared__ float bl[16];
    const int blk = blockIdx.x;
    const int row = blk >> 4;
    const int j = blk & 15;
    for (int i = threadIdx.x; i < BINS1; i += NTHREADS) h[i] = 0u;
    if (threadIdx.x < 16) bl[threadIdx.x] = boost[j * 16 + threadIdx.x];
    __syncthreads();
    const unsigned int p1 = bin1[row];
    const float4* __restrict__ xp =
        (const float4*)(x + (size_t)row * ROW_N + (size_t)j * SLICE);
    const int t = threadIdx.x;
#pragma unroll
    for (int i = 0; i < SLICE / (4 * NTHREADS); ++i) {
        const int idx4 = t + i * NTHREADS;
        float4 v = xp[idx4];
        const float b = bl[(idx4 * 4) >> 10];
        unsigned int k;
        k = f2key(v.x * b); if ((k >> 21) == p1) atomicAdd(&h[(k >> 10) & 0x7FFu], 1u);
        k = f2key(v.y * b); if ((k >> 21) == p1) atomicAdd(&h[(k >> 10) & 0x7FFu], 1u);
        k = f2key(v.z * b); if ((k >> 21) == p1) atomicAdd(&h[(k >> 10) & 0x7FFu], 1u);
        k = f2key(v.w * b); if ((k >> 21) == p1) atomicAdd(&h[(k >> 10) & 0x7FFu], 1u);
    }
    __syncthreads();
    unsigned int* __restrict__ gh = hist + (size_t)row * BINS1;
    for (int i = threadIdx.x; i < BINS1; i += NTHREADS)
        if (h[i]) atomicAdd(&gh[i], h[i]);
}

// Pass 3: histogram of low 10 bits for elements whose top-22 == prefix12.
__global__ void __launch_bounds__(NTHREADS) hist3_kernel(const float* __restrict__ x,
        const float* __restrict__ boost, const unsigned int* __restrict__ bin1,
        const unsigned int* __restrict__ bin2, unsigned int* __restrict__ hist) {
    __shared__ unsigned int h[BINS3];
    __shared__ float bl[16];
    const int blk = blockIdx.x;
    const int row = blk >> 4;
    const int j = blk & 15;
    for (int i = threadIdx.x; i < BINS3; i += NTHREADS) h[i] = 0u;
    if (threadIdx.x < 16) bl[threadIdx.x] = boost[j * 16 + threadIdx.x];
    __syncthreads();
    const unsigned int p12 = (bin1[row] << 11) | bin2[row];
    const float4* __restrict__ xp =
        (const float4*)(x + (size_t)row * ROW_N + (size_t)j * SLICE);
    const int t = threadIdx.x;
#pragma unroll
    for (int i = 0; i < SLICE / (4 * NTHREADS); ++i) {
        const int idx4 = t + i * NTHREADS;
        float4 v = xp[idx4];
        const float b = bl[(idx4 * 4) >> 10];
        unsigned int k;
        k = f2key(v.x * b); if ((k >> 10) == p12) atomicAdd(&h[k & 0x3FFu], 1u);
        k = f2key(v.y * b); if ((k >> 10) == p12) atomicAdd(&h[k & 0x3FFu], 1u);
        k = f2key(v.z * b); if ((k >> 10) == p12) atomicAdd(&h[k & 0x3FFu], 1u);
        k = f2key(v.w * b); if ((k >> 10) == p12) atomicAdd(&h[k & 0x3FFu], 1u);
    }
    __syncthreads();
    unsigned int* __restrict__ gh = hist + (size_t)row * BINS3;
    for (int i = threadIdx.x; i < BINS3; i += NTHREADS)
        if (h[i]) atomicAdd(&gh[i], h[i]);
}

// Per-row: find bin b with S_above(b) < k <= S_above(b)+h[b]; output b and
// remaining rank within the bin. One block per row.
template <int BINS>
__global__ void __launch_bounds__(NTHREADS) select_kernel(
        const unsigned int* __restrict__ hist,
        const unsigned int* __restrict__ k_in,   // null -> K_SEL
        unsigned int* __restrict__ bin_out,
        unsigned int* __restrict__ k_out) {      // may be null
    constexpr int PER = BINS / NTHREADS;
    const int row = blockIdx.x;
    const unsigned int* __restrict__ h = hist + (size_t)row * BINS;
    const int t = threadIdx.x;
    unsigned int loc[PER];
    unsigned int s = 0;
#pragma unroll
    for (int i = 0; i < PER; ++i) { loc[i] = h[t * PER + i]; s += loc[i]; }
    __shared__ unsigned int suf[NTHREADS];
    suf[t] = s;
    __syncthreads();
    for (int off = 1; off < NTHREADS; off <<= 1) {
        unsigned int v = (t + off < NTHREADS) ? suf[t + off] : 0u;
        __syncthreads();
        suf[t] += v;
        __syncthreads();
    }
    // suf[t] = sum of psum over threads >= t (inclusive suffix sum)
    const unsigned int above_chunk = (t + 1 < NTHREADS) ? suf[t + 1] : 0u;
    const unsigned int k = k_in ? k_in[row] : K_SEL;
    unsigned int cum = above_chunk;
#pragma unroll
    for (int i = PER - 1; i >= 0; --i) {
        if (k > cum && k <= cum + loc[i]) {
            bin_out[row] = (unsigned int)(t * PER + i);
            if (k_out) k_out[row] = k - cum;
        }
        cum += loc[i];
    }
}

// Final pass: out = x * (boosted >= thresh). Float compare (IEEE) matches JAX
// semantics incl. signed zeros; thresh is the exact k-th largest boosted value.
__global__ void __launch_bounds__(NTHREADS) mask_kernel(const float* __restrict__ x,
        const float* __restrict__ boost,
        const unsigned int* __restrict__ bin1, const unsigned int* __restrict__ bin2,
        const unsigned int* __restrict__ bin3, float* __restrict__ out) {
    __shared__ float bl[16];
    const int blk = blockIdx.x;
    const int row = blk >> 4;
    const int j = blk & 15;
    if (threadIdx.x < 16) bl[threadIdx.x] = boost[j * 16 + threadIdx.x];
    __syncthreads();
    const unsigned int tk = (bin1[row] << 21) | (bin2[row] << 10) | bin3[row];
    const float tf = key2f(tk);
    const size_t base = (size_t)row * ROW_N + (size_t)j * SLICE;
    const float4* __restrict__ xp = (const float4*)(x + base);
    float4* __restrict__ op = (float4*)(out + base);
    const int t = threadIdx.x;
#pragma unroll
    for (int i = 0; i < SLICE / (4 * NTHREADS); ++i) {
        const int idx4 = t + i * NTHREADS;
        float4 v = xp[idx4];
        const float b = bl[(idx4 * 4) >> 10];
        float4 o;
        o.x = (v.x * b >= tf) ? v.x : 0.0f;
        o.y = (v.y * b >= tf) ? v.y : 0.0f;
        o.z = (v.z * b >= tf) ? v.z : 0.0f;
        o.w = (v.w * b >= tf) ? v.w : 0.0f;
        op[idx4] = o;
    }
}

extern "C" void kernel_launch(void* const* d_in, const int* in_sizes, int n_in,
                              void* d_out, int out_size, void* d_ws, size_t ws_size,
                              hipStream_t stream) {
    const float* x = (const float*)d_in[0];
    const float* duty = (const float*)d_in[1];
    float* out = (float*)d_out;
    char* ws = (char*)d_ws;

    float* boost        = (float*)ws;                        // 1 KB
    unsigned int* bin1  = (unsigned int*)(ws + 1024);        // 512 B each
    unsigned int* k1    = (unsigned int*)(ws + 1024 + 512);
    unsigned int* bin2  = (unsigned int*)(ws + 1024 + 1024);
    unsigned int* k2    = (unsigned int*)(ws + 1024 + 1536);
    unsigned int* bin3  = (unsigned int*)(ws + 1024 + 2048);
    unsigned int* hist1 = (unsigned int*)(ws + 4096);        // 128*2048 u32 = 1 MB
    unsigned int* hist2 = hist1 + (size_t)NB * BINS1;        // 1 MB
    unsigned int* hist3 = hist2 + (size_t)NB * BINS1;        // 0.5 MB

    const size_t hist_bytes =
        ((size_t)NB * BINS1 * 2 + (size_t)NB * BINS3) * sizeof(unsigned int);
    hipMemsetAsync(hist1, 0, hist_bytes, stream);

    boost_kernel<<<1, NC, 0, stream>>>(duty, boost);
    hist1_kernel<<<NB * BPR, NTHREADS, 0, stream>>>(x, boost, hist1);
    select_kernel<BINS1><<<NB, NTHREADS, 0, stream>>>(hist1, nullptr, bin1, k1);
    hist2_kernel<<<NB * BPR, NTHREADS, 0, stream>>>(x, boost, bin1, hist2);
    select_kernel<BINS1><<<NB, NTHREADS, 0, stream>>>(hist2, k1, bin2, k2);
    hist3_kernel<<<NB * BPR, NTHREADS, 0, stream>>>(x, boost, bin1, bin2, hist3);
    select_kernel<BINS3><<<NB, NTHREADS, 0, stream>>>(hist3, k2, bin3, nullptr);
    mask_kernel<<<NB * BPR, NTHREADS, 0, stream>>>(x, boost, bin1, bin2, bin3, out);
}